// Round 1
// baseline (140.373 us; speedup 1.0000x reference)
//
#include <hip/hip_runtime.h>
#include <math.h>

// Problem constants (match reference)
#define T_TOTAL 8192
#define KK      10
#define DMODEL  256
#define BATCH   32
#define TPB     4          // t-rows per block
#define D4      (DMODEL/4) // 64 float4 per row
#define BSTRIDE4 ((size_t)T_TOTAL * D4)  // float4 stride between batches

__global__ __launch_bounds__(256) void gre_pos_add(
    const float* __restrict__ x,
    const float* __restrict__ emb,
    const float* __restrict__ mu,
    const float* __restrict__ sigma,
    float* __restrict__ out)
{
    const int tid = threadIdx.x;
    const int tl  = tid >> 6;   // 0..3  (row within block)
    const int c   = tid & 63;   // float4 column 0..63
    const int t   = blockIdx.x * TPB + tl;

    // --- softmax(log_p) over K=10 (stable, matches jax.nn.softmax) ---
    float lp[KK];
    float mx = -INFINITY;
#pragma unroll
    for (int k = 0; k < KK; ++k) {
        const float mk = mu[k];
        const float sk = sigma[k];
        const float a  = (float)t - mk;
        const float v  = -(a * a) / (2.0f * sk + 1e-8f)
                         - 0.5f * __logf(fabsf(sk) + 1e-8f);
        lp[k] = v;
        mx = fmaxf(mx, v);
    }
    float s = 0.0f;
#pragma unroll
    for (int k = 0; k < KK; ++k) {
        lp[k] = __expf(lp[k] - mx);
        s += lp[k];
    }
    const float inv = 1.0f / s;

    // --- pos_enc float4 for (t, c) : sum_k w[k] * emb[k][c*4..c*4+3] ---
    const float4* __restrict__ emb4 = (const float4*)emb;
    float4 pe = make_float4(0.f, 0.f, 0.f, 0.f);
#pragma unroll
    for (int k = 0; k < KK; ++k) {
        const float4 e = emb4[k * D4 + c];
        const float w  = lp[k] * inv;
        pe.x = fmaf(w, e.x, pe.x);
        pe.y = fmaf(w, e.y, pe.y);
        pe.z = fmaf(w, e.z, pe.z);
        pe.w = fmaf(w, e.w, pe.w);
    }

    // --- broadcast-add over batch: out[b][t][:] = x[b][t][:] + pe ---
    const float4* __restrict__ x4 = (const float4*)x;
    float4* __restrict__ o4       = (float4*)out;
    const size_t base = (size_t)t * D4 + c;

#pragma unroll 4
    for (int b = 0; b < BATCH; ++b) {
        const size_t idx = base + (size_t)b * BSTRIDE4;
        float4 v = x4[idx];
        v.x += pe.x; v.y += pe.y; v.z += pe.z; v.w += pe.w;
        o4[idx] = v;
    }
}

extern "C" void kernel_launch(void* const* d_in, const int* in_sizes, int n_in,
                              void* d_out, int out_size, void* d_ws, size_t ws_size,
                              hipStream_t stream) {
    const float* x     = (const float*)d_in[0];
    const float* emb   = (const float*)d_in[1];
    const float* mu    = (const float*)d_in[2];
    const float* sigma = (const float*)d_in[3];
    float* out         = (float*)d_out;

    const int blocks = T_TOTAL / TPB;  // 2048
    gre_pos_add<<<blocks, 256, 0, stream>>>(x, emb, mu, sigma, out);
}

// Round 2
// 88.836 us; speedup vs baseline: 1.5801x; 1.5801x over previous
//
#include <hip/hip_runtime.h>
#include <math.h>

// Problem constants (match reference)
#define T_TOTAL 8192
#define KK      10
#define DMODEL  256
#define BATCH   32
#define TPB     4                    // t-rows per block
#define D4      (DMODEL/4)           // 64 float4 per row
#define BSTRIDE4 ((size_t)T_TOTAL * D4)  // float4 stride between batches
#define BG      8                    // batches per block (BATCH / gridDim.y)

typedef float f32x4 __attribute__((ext_vector_type(4)));

__global__ __launch_bounds__(256) void gre_pos_add(
    const float* __restrict__ x,
    const float* __restrict__ emb,
    const float* __restrict__ mu,
    const float* __restrict__ sigma,
    float* __restrict__ out)
{
    const int tid = threadIdx.x;
    const int tl  = tid >> 6;   // 0..3  (row within block)
    const int c   = tid & 63;   // float4 column 0..63
    const int t   = blockIdx.x * TPB + tl;
    const int b0  = blockIdx.y * BG;

    // --- softmax(log_p) over K=10 (stable, matches jax.nn.softmax) ---
    float lp[KK];
    float mx = -INFINITY;
#pragma unroll
    for (int k = 0; k < KK; ++k) {
        const float mk = mu[k];
        const float sk = sigma[k];
        const float a  = (float)t - mk;
        const float v  = -(a * a) / (2.0f * sk + 1e-8f)
                         - 0.5f * __logf(fabsf(sk) + 1e-8f);
        lp[k] = v;
        mx = fmaxf(mx, v);
    }
    float s = 0.0f;
#pragma unroll
    for (int k = 0; k < KK; ++k) {
        lp[k] = __expf(lp[k] - mx);
        s += lp[k];
    }
    const float inv = 1.0f / s;

    // --- pos_enc float4 for (t, c) : sum_k w[k] * emb[k][c*4..c*4+3] ---
    const f32x4* __restrict__ emb4 = (const f32x4*)emb;
    f32x4 pe = (f32x4){0.f, 0.f, 0.f, 0.f};
#pragma unroll
    for (int k = 0; k < KK; ++k) {
        const f32x4 e = emb4[k * D4 + c];
        const float w = lp[k] * inv;
        pe += w * e;
    }

    // --- broadcast-add over BG batches: out[b][t][:] = x[b][t][:] + pe ---
    const f32x4* __restrict__ x4 = (const f32x4*)x;
    f32x4* __restrict__ o4       = (f32x4*)out;
    const size_t base = (size_t)t * D4 + c + (size_t)b0 * BSTRIDE4;

    // Phase 1: issue all BG loads (8 outstanding 16B/lane requests)
    f32x4 v[BG];
#pragma unroll
    for (int i = 0; i < BG; ++i) {
        v[i] = x4[base + (size_t)i * BSTRIDE4];
    }
    // Phase 2: add + non-temporal store (don't let the write stream evict x from LLC)
#pragma unroll
    for (int i = 0; i < BG; ++i) {
        f32x4 r = v[i] + pe;
        __builtin_nontemporal_store(r, &o4[base + (size_t)i * BSTRIDE4]);
    }
}

extern "C" void kernel_launch(void* const* d_in, const int* in_sizes, int n_in,
                              void* d_out, int out_size, void* d_ws, size_t ws_size,
                              hipStream_t stream) {
    const float* x     = (const float*)d_in[0];
    const float* emb   = (const float*)d_in[1];
    const float* mu    = (const float*)d_in[2];
    const float* sigma = (const float*)d_in[3];
    float* out         = (float*)d_out;

    dim3 grid(T_TOTAL / TPB, BATCH / BG);  // 2048 x 4 = 8192 blocks
    gre_pos_add<<<grid, 256, 0, stream>>>(x, emb, mu, sigma, out);
}